// Round 11
// baseline (235.891 us; speedup 1.0000x reference)
//
#include <hip/hip_runtime.h>
#include <stdint.h>
#include <math.h>

#define N_ROWS 8192
#define DDIM   512

typedef int   i32x8  __attribute__((ext_vector_type(8)));
typedef float f32x16 __attribute__((ext_vector_type(16)));

// scales: e8m0 123 = 2^-4 per operand -> 2^-8 combined, cancels the 16x
// pre-scale on each side. Replicated in all 4 bytes (opsel-proof).
#define SCALE_I32 0x7B7B7B7B
#define MFMA_SC(a, b, c) \
    __builtin_amdgcn_mfma_scale_f32_32x32x64_f8f6f4( \
        (a), (b), (c), 0 /*cbsz: fp8 e4m3*/, 0 /*blgp: fp8 e4m3*/, \
        0, SCALE_I32, 0, SCALE_I32)

// ---------------- f32 -> fp8 e4m3 (x16 pre-scale) ----------------
__device__ inline uint8_t f2fp8_sw(float x) {   // software RNE fallback
    const uint32_t sgn = (__float_as_uint(x) >> 31) << 7;
    float ax = fabsf(x);
    if (!(ax < 448.f)) return (uint8_t)(sgn | 0x7E);
    if (ax < 0.015625f) {                        // subnormal region, q*2^-9
        int q = (int)rintf(ax * 512.f);          // q in 0..8 (8 -> 2^-6 normal)
        return (uint8_t)(sgn | (uint32_t)q);
    }
    int e; float m = frexpf(ax, &e);             // ax = m*2^e, m in [0.5,1)
    int q = (int)rintf(m * 16.f);                // 8..16
    if (q == 16) { q = 8; e += 1; }
    return (uint8_t)(sgn | (uint32_t)(((e - 1 + 7) << 3) | (q - 8)));
}

__device__ inline int pk4(float a, float b, float c, float d) {
#if __has_builtin(__builtin_amdgcn_cvt_pk_fp8_f32)
    int r = __builtin_amdgcn_cvt_pk_fp8_f32(a, b, 0, false);
    r     = __builtin_amdgcn_cvt_pk_fp8_f32(c, d, r, true);
    return r;
#else
    return (int)f2fp8_sw(a) | ((int)f2fp8_sw(b) << 8) |
           ((int)f2fp8_sw(c) << 16) | ((int)f2fp8_sw(d) << 24);
#endif
}

__global__ void convert_fp8(const float* __restrict__ a, const float* __restrict__ b,
                            uint32_t* __restrict__ a8, uint32_t* __restrict__ b8) {
    const int i = blockIdx.x * 256 + threadIdx.x;        // 8 elems/thread
    const float4 va0 = ((const float4*)a)[2 * i];
    const float4 va1 = ((const float4*)a)[2 * i + 1];
    const float4 vb0 = ((const float4*)b)[2 * i];
    const float4 vb1 = ((const float4*)b)[2 * i + 1];
    uint2 ra, rb;
    ra.x = (uint32_t)pk4(va0.x * 16.f, va0.y * 16.f, va0.z * 16.f, va0.w * 16.f);
    ra.y = (uint32_t)pk4(va1.x * 16.f, va1.y * 16.f, va1.z * 16.f, va1.w * 16.f);
    rb.x = (uint32_t)pk4(vb0.x * 16.f, vb0.y * 16.f, vb0.z * 16.f, vb0.w * 16.f);
    rb.y = (uint32_t)pk4(vb1.x * 16.f, vb1.y * 16.f, vb1.z * 16.f, vb1.w * 16.f);
    ((uint2*)a8)[i] = ra;
    ((uint2*)b8)[i] = rb;
}

// ---------------- async global->LDS 16B stage ----------------
__device__ inline void stage16(const uint8_t* g, uint8_t* lds_wave_base) {
#if __has_builtin(__builtin_amdgcn_global_load_lds)
    __builtin_amdgcn_global_load_lds(
        (const __attribute__((address_space(1))) uint32_t*)g,
        (__attribute__((address_space(3))) uint32_t*)lds_wave_base, 16, 0, 0);
#else
    *(int4*)(lds_wave_base) = *(const int4*)g;
#endif
}

// ============================================================================
// R11: MX-fp8 port. 256x256 tile, BK=128 (4 K-tiles), 8 waves (2Mx4N),
// mfma_scale_f32_32x32x64_f8f6f4 with constant 2^-4 scales (values stored
// x16). LDS geometry BYTE-IDENTICAL to the proven bf16 kernel: 256 rows x
// 128B per operand per buffer, XOR granule swizzle slot=g^(row&7), staging
// source inverse-swizzled / linear LDS dest (absmax 0 in R5-R10).
// Per k-step (K=64): 12 ds_read_b128 (A 4 frags x 32B, B 2 x 32B); per tile
// 2 k-steps, 16 mfma_scale. R7 loop skeleton (reg-dbuf, 1 vmcnt+barrier/tile).
// Operand layout: lane = row (l&31), k = (l>>5)*32 + byte, reg-ascending.
// C/D layout shape-determined (verified m121-128) = R6's 32x32 epilogue.
// ============================================================================
__global__ void __launch_bounds__(512, 2)
clip_gemm(const uint8_t* __restrict__ A, const uint8_t* __restrict__ B,
          const float* __restrict__ scale_p,
          float* __restrict__ rowsum, float* __restrict__ colsum,
          float* __restrict__ diag) {
    __shared__ __attribute__((aligned(16))) uint8_t sh[131072];

    const int t    = threadIdx.x;
    const int wave = t >> 6;
    const int lane = t & 63;
    const int wm   = wave >> 2;    // 0..1  (M half: 128 rows)
    const int wn   = wave & 3;     // 0..3  (N slice: 64 cols)
    const int l31  = lane & 31;
    const int hl   = lane >> 5;    // k-half within k-step
    const int l7   = lane & 7;

    // 2D-chunked XCD swizzle (proven): xcd owns 8bm x 16bn, bm-fastest.
    const int orig = blockIdx.x;               // 0..1023
    const int xcd  = orig & 7;
    const int idx  = orig >> 3;                // 0..127
    const int bm   = (xcd & 3) * 8  + (idx & 7);
    const int bn   = (xcd >> 2) * 16 + (idx >> 3);

    const float s     = *scale_p;
    const float shift = s - 64.0f;

    f32x16 acc[4][2];
#pragma unroll
    for (int mi = 0; mi < 4; ++mi)
#pragma unroll
        for (int nj = 0; nj < 2; ++nj)
#pragma unroll
            for (int q = 0; q < 16; ++q) acc[mi][nj][q] = 0.0f;

    // staging source (inverse-swizzled): thread t supplies row c*64+(t>>3),
    // granule (t&7)^((t>>3)&7) of the 128B k-window of tile kt. fp8 rows: 512B.
    const int g16 = (((t & 7) ^ ((t >> 3) & 7)) << 4);
    const uint8_t* srcA = A + (size_t)(bm * 256 + (t >> 3)) * 512 + g16;
    const uint8_t* srcB = B + (size_t)(bn * 256 + (t >> 3)) * 512 + g16;
    uint8_t* dA = sh + wave * 1024;
    uint8_t* dB = sh + 32768 + wave * 1024;

#define STAGE8(kt, bsel) do {                                                   \
        _Pragma("unroll")                                                       \
        for (int c = 0; c < 4; ++c) {                                           \
            stage16(srcA + (size_t)(kt) * 128 + (size_t)c * 32768,              \
                    dA + (bsel) * 65536 + c * 8192);                            \
            stage16(srcB + (size_t)(kt) * 128 + (size_t)c * 32768,              \
                    dB + (bsel) * 65536 + c * 8192);                            \
        }                                                                       \
    } while (0)

    // fragment read offsets: granule (ks*4 + hl*2 + c) ^ (row&7); row&7 = l7.
    // lo/hi 16B of a lane's 32B differ by addr^16; k-steps differ by ^64.
    const int x0   = (((hl * 2)) ^ l7) << 4;       // ks=0, c=0
    const int x1   = x0 ^ 64;                      // ks=1, c=0
    const int aRow = (wm * 128 + l31) * 128;
    const int bRow = 32768 + (wn * 64 + l31) * 128;

    i32x8 aC[4], bC[2], aN[4], bN[2];

#define FRAG(dst, p, off) do {                                                  \
        int4 _lo = *(const int4*)((p) + (off));                                 \
        int4 _hi = *(const int4*)((p) + ((off) ^ 16));                          \
        dst = (i32x8){_lo.x, _lo.y, _lo.z, _lo.w, _hi.x, _hi.y, _hi.z, _hi.w};  \
    } while (0)

    // 12 ds_read_b128 for one k-step: A mi=0..3 (stride 32 rows = 4096B), B nj=0..1
#define LOAD12(AF, BF, BASE, X) do {                                            \
        const uint8_t* _a = (BASE) + aRow;                                      \
        const uint8_t* _bb = (BASE) + bRow;                                     \
        FRAG(AF[0], _a, (X));            FRAG(AF[1], _a, 4096 + (X));           \
        FRAG(AF[2], _a, 8192 + (X));     FRAG(AF[3], _a, 12288 + (X));          \
        FRAG(BF[0], _bb, (X));           FRAG(BF[1], _bb, 4096 + (X));          \
    } while (0)

#define MMA8(AF, BF) do {                                                       \
        __builtin_amdgcn_s_setprio(1);                                          \
        _Pragma("unroll")                                                       \
        for (int mi = 0; mi < 4; ++mi)                                          \
            _Pragma("unroll")                                                   \
            for (int nj = 0; nj < 2; ++nj)                                      \
                acc[mi][nj] = MFMA_SC(AF[mi], BF[nj], acc[mi][nj]);             \
        __builtin_amdgcn_s_setprio(0);                                          \
    } while (0)

    // ---------------- prologue: stage tiles 0,1 ----------------
    STAGE8(0, 0);
    STAGE8(1, 1);
    asm volatile("s_waitcnt vmcnt(8)" ::: "memory");   // tile 0 resident (own)
    __builtin_amdgcn_s_barrier();                      // -> all waves'
    LOAD12(aC, bC, sh, x0);                            // tile 0, ks=0

    // ---------------- main loop: 4 K-tiles of 128 ----------------
    for (int tt = 0; tt < 4; ++tt) {
        const uint8_t* base  = sh + (tt & 1) * 65536;
        const uint8_t* obase = sh + ((tt + 1) & 1) * 65536;

        LOAD12(aN, bN, base, x1);                      // this tile, ks=1
        MMA8(aC, bC);                                  // ks=0

        asm volatile("s_waitcnt vmcnt(0)" ::: "memory");
        __builtin_amdgcn_s_barrier();                  // buffer fully read & next resident

        if (tt < 2) STAGE8(tt + 2, tt & 1);
        if (tt < 3) LOAD12(aC, bC, obase, x0);         // next tile, ks=0
        MMA8(aN, bN);                                  // ks=1
    }
#undef STAGE8
#undef LOAD12
#undef FRAG
#undef MMA8

    // ---------------- epilogue: exp + reductions (R6-verified 32x32) -------
    // C/D: col = lane&31, row = (q&3) + 8*(q>>2) + 4*(lane>>5)
    float cp0 = 0.f, cp1 = 0.f;
#pragma unroll
    for (int mi = 0; mi < 4; ++mi) {
        float rp[16];
#pragma unroll
        for (int q = 0; q < 16; ++q) rp[q] = 0.f;
#pragma unroll
        for (int q = 0; q < 16; ++q) {
            const float l0 = s * acc[mi][0][q];
            const float l1 = s * acc[mi][1][q];
            const float e0 = __expf(l0 - shift);
            const float e1 = __expf(l1 - shift);
            rp[q] = e0 + e1;
            cp0 += e0;
            cp1 += e1;
        }
#pragma unroll
        for (int q = 0; q < 16; ++q) {
            float v = rp[q];
            v += __shfl_xor(v, 1);
            v += __shfl_xor(v, 2);
            v += __shfl_xor(v, 4);
            v += __shfl_xor(v, 8);
            v += __shfl_xor(v, 16);
            if (l31 == 0) {
                const int rr = wm * 128 + mi * 32 + (q & 3) + 8 * (q >> 2) + 4 * hl;
                atomicAdd(&rowsum[bm * 256 + rr], v);
            }
        }
    }
    cp0 += __shfl_xor(cp0, 32);
    cp1 += __shfl_xor(cp1, 32);
    if (hl == 0) {
        atomicAdd(&colsum[bn * 256 + wn * 64 + l31], cp0);
        atomicAdd(&colsum[bn * 256 + wn * 64 + 32 + l31], cp1);
    }
    if (bm == bn) {
#pragma unroll
        for (int mi = 0; mi < 4; ++mi)
#pragma unroll
            for (int nj = 0; nj < 2; ++nj)
#pragma unroll
                for (int q = 0; q < 16; ++q) {
                    const int rr = wm * 128 + mi * 32 + (q & 3) + 8 * (q >> 2) + 4 * hl;
                    const int cc = wn * 64 + nj * 32 + l31;
                    if (rr == cc)
                        diag[bm * 256 + rr] = s * acc[mi][nj][q];
                }
    }
}

// ---------------- final reduce: loss scalar (parallel) ----------------
__global__ void clip_finalize(const float* __restrict__ rowsum, const float* __restrict__ colsum,
                              const float* __restrict__ diag, const float* __restrict__ scale_p,
                              float* __restrict__ out) {
    __shared__ float red[4];
    const float s = *scale_p;
    const float shift = s - 64.0f;
    const int i = blockIdx.x * 256 + threadIdx.x;   // grid 32 x 256 = 8192
    float acc = logf(rowsum[i]) + logf(colsum[i]) + 2.f * shift - 2.f * diag[i];
#pragma unroll
    for (int m = 1; m < 64; m <<= 1) acc += __shfl_xor(acc, m);
    const int wave = threadIdx.x >> 6;
    const int lane = threadIdx.x & 63;
    if (lane == 0) red[wave] = acc;
    __syncthreads();
    if (threadIdx.x == 0) {
        atomicAdd(out, (red[0] + red[1] + red[2] + red[3]) / (2.0f * N_ROWS));
    }
}

extern "C" void kernel_launch(void* const* d_in, const int* in_sizes, int n_in,
                              void* d_out, int out_size, void* d_ws, size_t ws_size,
                              hipStream_t stream) {
    const float* img     = (const float*)d_in[0];
    const float* txt     = (const float*)d_in[1];
    const float* scale_p = (const float*)d_in[2];

    uint8_t* ws = (uint8_t*)d_ws;
    uint32_t* A8    = (uint32_t*)ws;                                  // 4 MB
    uint32_t* B8    = (uint32_t*)(ws + (size_t)4 * 1024 * 1024);      // 4 MB
    float*    rowsum = (float*)(ws + (size_t)8 * 1024 * 1024);        // 32 KB
    float*    colsum = rowsum + N_ROWS;                               // 32 KB
    float*    diag   = colsum + N_ROWS;                               // 32 KB
    float*    out    = (float*)d_out;

    hipMemsetAsync(rowsum, 0, 2 * N_ROWS * sizeof(float), stream);
    hipMemsetAsync(out, 0, sizeof(float), stream);
    convert_fp8<<<2048, 256, 0, stream>>>(img, txt, A8, B8);
    clip_gemm<<<1024, 512, 0, stream>>>((const uint8_t*)A8, (const uint8_t*)B8,
                                        scale_p, rowsum, colsum, diag);
    clip_finalize<<<32, 256, 0, stream>>>(rowsum, colsum, diag, scale_p, out);
}

// Round 12
// 218.221 us; speedup vs baseline: 1.0810x; 1.0810x over previous
//
#include <hip/hip_runtime.h>
#include <stdint.h>
#include <math.h>

#define N_ROWS 8192
#define DDIM   512

typedef int   i32x8  __attribute__((ext_vector_type(8)));
typedef float f32x16 __attribute__((ext_vector_type(16)));

// scales: e8m0 123 = 2^-4 per operand -> 2^-8 combined, cancels the 16x
// pre-scale on each side. Replicated in all 4 bytes (opsel-proof).
#define SCALE_I32 0x7B7B7B7B
#define MFMA_SC(a, b, c) \
    __builtin_amdgcn_mfma_scale_f32_32x32x64_f8f6f4( \
        (a), (b), (c), 0 /*cbsz: fp8 e4m3*/, 0 /*blgp: fp8 e4m3*/, \
        0, SCALE_I32, 0, SCALE_I32)

// ---------------- f32 -> fp8 e4m3 (x16 pre-scale) ----------------
__device__ inline uint8_t f2fp8_sw(float x) {   // software RNE fallback
    const uint32_t sgn = (__float_as_uint(x) >> 31) << 7;
    float ax = fabsf(x);
    if (!(ax < 448.f)) return (uint8_t)(sgn | 0x7E);
    if (ax < 0.015625f) {
        int q = (int)rintf(ax * 512.f);
        return (uint8_t)(sgn | (uint32_t)q);
    }
    int e; float m = frexpf(ax, &e);
    int q = (int)rintf(m * 16.f);
    if (q == 16) { q = 8; e += 1; }
    return (uint8_t)(sgn | (uint32_t)(((e - 1 + 7) << 3) | (q - 8)));
}

__device__ inline int pk4(float a, float b, float c, float d) {
#if __has_builtin(__builtin_amdgcn_cvt_pk_fp8_f32)
    int r = __builtin_amdgcn_cvt_pk_fp8_f32(a, b, 0, false);
    r     = __builtin_amdgcn_cvt_pk_fp8_f32(c, d, r, true);
    return r;
#else
    return (int)f2fp8_sw(a) | ((int)f2fp8_sw(b) << 8) |
           ((int)f2fp8_sw(c) << 16) | ((int)f2fp8_sw(d) << 24);
#endif
}

__global__ void convert_fp8(const float* __restrict__ a, const float* __restrict__ b,
                            uint32_t* __restrict__ a8, uint32_t* __restrict__ b8) {
    const int i = blockIdx.x * 256 + threadIdx.x;        // 8 elems/thread
    const float4 va0 = ((const float4*)a)[2 * i];
    const float4 va1 = ((const float4*)a)[2 * i + 1];
    const float4 vb0 = ((const float4*)b)[2 * i];
    const float4 vb1 = ((const float4*)b)[2 * i + 1];
    uint2 ra, rb;
    ra.x = (uint32_t)pk4(va0.x * 16.f, va0.y * 16.f, va0.z * 16.f, va0.w * 16.f);
    ra.y = (uint32_t)pk4(va1.x * 16.f, va1.y * 16.f, va1.z * 16.f, va1.w * 16.f);
    rb.x = (uint32_t)pk4(vb0.x * 16.f, vb0.y * 16.f, vb0.z * 16.f, vb0.w * 16.f);
    rb.y = (uint32_t)pk4(vb1.x * 16.f, vb1.y * 16.f, vb1.z * 16.f, vb1.w * 16.f);
    ((uint2*)a8)[i] = ra;
    ((uint2*)b8)[i] = rb;
}

// ---------------- async global->LDS 16B stage ----------------
__device__ inline void stage16(const uint8_t* g, uint8_t* lds_wave_base) {
#if __has_builtin(__builtin_amdgcn_global_load_lds)
    __builtin_amdgcn_global_load_lds(
        (const __attribute__((address_space(1))) uint32_t*)g,
        (__attribute__((address_space(3))) uint32_t*)lds_wave_base, 16, 0, 0);
#else
    *(int4*)(lds_wave_base) = *(const int4*)g;
#endif
}

// ============================================================================
// R12: fp8 with spill-proof register budget. R11 spilled (~259 VGPR needed >
// 256 cap for 8-wave residency -> 760 MB scratch traffic). Fix: NO fragment
// double-buffering (48 frag regs live instead of 96); lockstep load->MMA per
// k-step (schedule shape proven irrelevant R5-R10). Swizzle upgraded to
// s(r) = (r ^ (r>>3)) & 7 so lanes r,r+8,r+16,r+24 get distinct slots
// (kills R11's 4-way conflict). Both sides consistent: staging source
// supplies granule (t&7)^((t>>3)&7)^((t>>6)&7); read slot = g ^ s(r).
// 256x256 tile, BK=128, 4 K-tiles, mfma_scale_f32_32x32x64_f8f6f4, constant
// 2^-4 scales (values stored x16). Epilogue = R11's (absmax 0.0 verified).
// ============================================================================
__global__ void __launch_bounds__(512, 2)
clip_gemm(const uint8_t* __restrict__ A, const uint8_t* __restrict__ B,
          const float* __restrict__ scale_p,
          float* __restrict__ rowsum, float* __restrict__ colsum,
          float* __restrict__ diag) {
    __shared__ __attribute__((aligned(16))) uint8_t sh[131072];

    const int t    = threadIdx.x;
    const int wave = t >> 6;
    const int lane = t & 63;
    const int wm   = wave >> 2;    // 0..1  (M half: 128 rows)
    const int wn   = wave & 3;     // 0..3  (N slice: 64 cols)
    const int l31  = lane & 31;
    const int hl   = lane >> 5;    // k-half within k-step
    const int l7   = lane & 7;
    const int u    = (lane >> 3) & 3;   // row bits 3..4

    // 2D-chunked XCD swizzle (proven): xcd owns 8bm x 16bn, bm-fastest.
    const int orig = blockIdx.x;               // 0..1023
    const int xcd  = orig & 7;
    const int idx  = orig >> 3;                // 0..127
    const int bm   = (xcd & 3) * 8  + (idx & 7);
    const int bn   = (xcd >> 2) * 16 + (idx >> 3);

    const float s     = *scale_p;
    const float shift = s - 64.0f;

    f32x16 acc[4][2];
#pragma unroll
    for (int mi = 0; mi < 4; ++mi)
#pragma unroll
        for (int nj = 0; nj < 2; ++nj)
#pragma unroll
            for (int q = 0; q < 16; ++q) acc[mi][nj][q] = 0.0f;

    // staging source: thread t supplies LDS row c*64+(t>>3), granule
    // (t&7) ^ s(row) with s(row) = ((t>>3)&7) ^ ((t>>6)&7)  (c-independent).
    const int g16 = (((t & 7) ^ ((t >> 3) & 7) ^ ((t >> 6) & 7)) << 4);
    const uint8_t* srcA = A + (size_t)(bm * 256 + (t >> 3)) * 512 + g16;
    const uint8_t* srcB = B + (size_t)(bn * 256 + (t >> 3)) * 512 + g16;
    uint8_t* dA = sh + wave * 1024;
    uint8_t* dB = sh + 32768 + wave * 1024;

#define STAGE8(kt, bsel) do {                                                   \
        _Pragma("unroll")                                                       \
        for (int c = 0; c < 4; ++c) {                                           \
            stage16(srcA + (size_t)(kt) * 128 + (size_t)c * 32768,              \
                    dA + (bsel) * 65536 + c * 8192);                            \
            stage16(srcB + (size_t)(kt) * 128 + (size_t)c * 32768,              \
                    dB + (bsel) * 65536 + c * 8192);                            \
        }                                                                       \
    } while (0)

    // fragment read: granule g = ks*4 + hl*2 (+1 for hi 16B), stored at slot
    // g ^ s(r); s(r) = l7 ^ u for even mi/nj, ^4 more for odd (row +32).
    // X = base slot-offset for (ks=0, even frag); odd frag -> ^64; ks=1 -> ^64.
    const int X    = (((hl * 2)) ^ l7 ^ u) << 4;
    const int aRow = (wm * 128 + l31) * 128;
    const int bRow = 32768 + (wn * 64 + l31) * 128;

    i32x8 aC[4], bC[2];

#define FRAG(dst, p, off) do {                                                  \
        const int4 _lo = *(const int4*)((p) + (off));                           \
        const int4 _hi = *(const int4*)((p) + ((off) ^ 16));                    \
        dst = (i32x8){_lo.x, _lo.y, _lo.z, _lo.w, _hi.x, _hi.y, _hi.z, _hi.w};  \
    } while (0)

    // 12 ds_read_b128 for one k-step (XK = ks*64)
#define LOAD6(BASE, XK) do {                                                    \
        const uint8_t* _a  = (BASE) + aRow;                                     \
        const uint8_t* _bb = (BASE) + bRow;                                     \
        FRAG(aC[0], _a,  X ^ (XK));            FRAG(aC[1], _a,  4096  + (X ^ 64 ^ (XK))); \
        FRAG(aC[2], _a,  8192 + (X ^ (XK)));   FRAG(aC[3], _a,  12288 + (X ^ 64 ^ (XK))); \
        FRAG(bC[0], _bb, X ^ (XK));            FRAG(bC[1], _bb, 4096  + (X ^ 64 ^ (XK))); \
    } while (0)

#define MMA8() do {                                                             \
        __builtin_amdgcn_s_setprio(1);                                          \
        _Pragma("unroll")                                                       \
        for (int mi = 0; mi < 4; ++mi)                                          \
            _Pragma("unroll")                                                   \
            for (int nj = 0; nj < 2; ++nj)                                      \
                acc[mi][nj] = MFMA_SC(aC[mi], bC[nj], acc[mi][nj]);             \
        __builtin_amdgcn_s_setprio(0);                                          \
    } while (0)

    // ---------------- prologue: stage tiles 0,1 ----------------
    STAGE8(0, 0);
    STAGE8(1, 1);
    asm volatile("s_waitcnt vmcnt(8)" ::: "memory");   // tile 0 resident (own)
    __builtin_amdgcn_s_barrier();                      // -> all waves'

    // ---------------- main loop: 4 K-tiles of 128 ----------------
    for (int tt = 0; tt < 4; ++tt) {
        const uint8_t* base = sh + (tt & 1) * 65536;

        LOAD6(base, 0);   MMA8();                      // ks=0
        LOAD6(base, 64);  MMA8();                      // ks=1

        // own staging loads (issued at tt-1 for tile tt+1) drained; barrier
        // makes it collective AND separates reads of `base` from overwrite.
        asm volatile("s_waitcnt vmcnt(0)" ::: "memory");
        __builtin_amdgcn_s_barrier();

        if (tt < 2) STAGE8(tt + 2, tt & 1);
    }
#undef STAGE8
#undef LOAD6
#undef FRAG
#undef MMA8

    // ---------------- epilogue: exp + reductions (R11-verified 32x32) ------
    // C/D: col = lane&31, row = (q&3) + 8*(q>>2) + 4*(lane>>5)
    float cp0 = 0.f, cp1 = 0.f;
#pragma unroll
    for (int mi = 0; mi < 4; ++mi) {
        float rp[16];
#pragma unroll
        for (int q = 0; q < 16; ++q) rp[q] = 0.f;
#pragma unroll
        for (int q = 0; q < 16; ++q) {
            const float l0 = s * acc[mi][0][q];
            const float l1 = s * acc[mi][1][q];
            const float e0 = __expf(l0 - shift);
            const float e1 = __expf(l1 - shift);
            rp[q] = e0 + e1;
            cp0 += e0;
            cp1 += e1;
        }
#pragma unroll
        for (int q = 0; q < 16; ++q) {
            float v = rp[q];
            v += __shfl_xor(v, 1);
            v += __shfl_xor(v, 2);
            v += __shfl_xor(v, 4);
            v += __shfl_xor(v, 8);
            v += __shfl_xor(v, 16);
            if (l31 == 0) {
                const int rr = wm * 128 + mi * 32 + (q & 3) + 8 * (q >> 2) + 4 * hl;
                atomicAdd(&rowsum[bm * 256 + rr], v);
            }
        }
    }
    cp0 += __shfl_xor(cp0, 32);
    cp1 += __shfl_xor(cp1, 32);
    if (hl == 0) {
        atomicAdd(&colsum[bn * 256 + wn * 64 + l31], cp0);
        atomicAdd(&colsum[bn * 256 + wn * 64 + 32 + l31], cp1);
    }
    if (bm == bn) {
#pragma unroll
        for (int mi = 0; mi < 4; ++mi)
#pragma unroll
            for (int nj = 0; nj < 2; ++nj)
#pragma unroll
                for (int q = 0; q < 16; ++q) {
                    const int rr = wm * 128 + mi * 32 + (q & 3) + 8 * (q >> 2) + 4 * hl;
                    const int cc = wn * 64 + nj * 32 + l31;
                    if (rr == cc)
                        diag[bm * 256 + rr] = s * acc[mi][nj][q];
                }
    }
}

// ---------------- final reduce: loss scalar (parallel) ----------------
__global__ void clip_finalize(const float* __restrict__ rowsum, const float* __restrict__ colsum,
                              const float* __restrict__ diag, const float* __restrict__ scale_p,
                              float* __restrict__ out) {
    __shared__ float red[4];
    const float s = *scale_p;
    const float shift = s - 64.0f;
    const int i = blockIdx.x * 256 + threadIdx.x;   // grid 32 x 256 = 8192
    float acc = logf(rowsum[i]) + logf(colsum[i]) + 2.f * shift - 2.f * diag[i];
#pragma unroll
    for (int m = 1; m < 64; m <<= 1) acc += __shfl_xor(acc, m);
    const int wave = threadIdx.x >> 6;
    const int lane = threadIdx.x & 63;
    if (lane == 0) red[wave] = acc;
    __syncthreads();
    if (threadIdx.x == 0) {
        atomicAdd(out, (red[0] + red[1] + red[2] + red[3]) / (2.0f * N_ROWS));
    }
}

extern "C" void kernel_launch(void* const* d_in, const int* in_sizes, int n_in,
                              void* d_out, int out_size, void* d_ws, size_t ws_size,
                              hipStream_t stream) {
    const float* img     = (const float*)d_in[0];
    const float* txt     = (const float*)d_in[1];
    const float* scale_p = (const float*)d_in[2];

    uint8_t* ws = (uint8_t*)d_ws;
    uint32_t* A8    = (uint32_t*)ws;                                  // 4 MB
    uint32_t* B8    = (uint32_t*)(ws + (size_t)4 * 1024 * 1024);      // 4 MB
    float*    rowsum = (float*)(ws + (size_t)8 * 1024 * 1024);        // 32 KB
    float*    colsum = rowsum + N_ROWS;                               // 32 KB
    float*    diag   = colsum + N_ROWS;                               // 32 KB
    float*    out    = (float*)d_out;

    hipMemsetAsync(rowsum, 0, 2 * N_ROWS * sizeof(float), stream);
    hipMemsetAsync(out, 0, sizeof(float), stream);
    convert_fp8<<<2048, 256, 0, stream>>>(img, txt, A8, B8);
    clip_gemm<<<1024, 512, 0, stream>>>((const uint8_t*)A8, (const uint8_t*)B8,
                                        scale_p, rowsum, colsum, diag);
    clip_finalize<<<32, 256, 0, stream>>>(rowsum, colsum, diag, scale_p, out);
}

// Round 13
// 149.280 us; speedup vs baseline: 1.5802x; 1.4618x over previous
//
#include <hip/hip_runtime.h>
#include <stdint.h>

#define N_ROWS 8192
#define DDIM   512

typedef __bf16 bf16_t;
typedef bf16_t bf16x8 __attribute__((ext_vector_type(8)));
typedef float  f32x4  __attribute__((ext_vector_type(4)));

#define MFMA16 __builtin_amdgcn_mfma_f32_16x16x32_bf16

// ---------------- f32 -> bf16 (RNE) convert, vectorized ----------------
__device__ inline uint16_t f2bf(float f) {
    uint32_t u = __float_as_uint(f);
    u += 0x7FFFu + ((u >> 16) & 1u);
    return (uint16_t)(u >> 16);
}

__global__ void convert_bf16(const float* __restrict__ a, const float* __restrict__ b,
                             uint16_t* __restrict__ abf, uint16_t* __restrict__ bbf) {
    const int quads = N_ROWS * DDIM / 4;
    const int stride = gridDim.x * blockDim.x;
    for (int i = blockIdx.x * blockDim.x + threadIdx.x; i < quads; i += stride) {
        float4 va = ((const float4*)a)[i];
        float4 vb = ((const float4*)b)[i];
        ushort4 ra, rb;
        ra.x = f2bf(va.x); ra.y = f2bf(va.y); ra.z = f2bf(va.z); ra.w = f2bf(va.w);
        rb.x = f2bf(vb.x); rb.y = f2bf(vb.y); rb.z = f2bf(vb.z); rb.w = f2bf(vb.w);
        ((ushort4*)abf)[i] = ra;
        ((ushort4*)bbf)[i] = rb;
    }
}

// ---------------- async global->LDS 16B stage ----------------
__device__ inline void stage16(const uint8_t* g, uint8_t* lds_wave_base) {
#if __has_builtin(__builtin_amdgcn_global_load_lds)
    __builtin_amdgcn_global_load_lds(
        (const __attribute__((address_space(1))) uint32_t*)g,
        (__attribute__((address_space(3))) uint32_t*)lds_wave_base, 16, 0, 0);
#else
    *(int4*)(lds_wave_base) = *(const int4*)g;
#endif
}

// ============================================================================
// R13: ZERO-BARRIER main loop. R9 proved stage/ds_read/MFMA serialize under
// any in-loop barrier scheme (R5-R10 all ~30% MfmaUtil). Structure change:
//  - A tile (128 rows x K=512 = 128 KB) staged to LDS ONCE (16 stage16/thread,
//    one vmcnt(0)+barrier). Never overwritten -> no WAR sync, no LDS writes in
//    the loop -> no compiler alias drains.
//  - B read directly global->VGPR (L2-resident via XCD chunking), register
//    ping-pong, fully unrolled (static indices).
//  - 8 waves x (128 rows x 32 cols) each; 16 k-steps x 16 MFMA; waves free-run
//    (2/SIMD m114 overlap finally applies).
// LDS layout: row r (1024B), granule g (16B) at slot g^(r&7) -> ds_read_b128
// slot (ks*4+lg)^(lr&7): same conflict-free family as R5/R7 (measured 0).
// Staging source granule lane^wave (rule #21 both-sides).
// Epilogue: LDS-combined reductions (A region reused), 384 atomics/block.
// ============================================================================
__global__ void __launch_bounds__(512, 2)
clip_gemm(const uint16_t* __restrict__ A, const uint16_t* __restrict__ B,
          const float* __restrict__ scale_p,
          float* __restrict__ rowsum, float* __restrict__ colsum,
          float* __restrict__ diag) {
    __shared__ __attribute__((aligned(16))) uint8_t sh[131072];   // A: 128 x 1KB

    const int t    = threadIdx.x;
    const int wave = t >> 6;       // 0..7 : N slice (32 cols each)
    const int lane = t & 63;
    const int lr   = lane & 15;
    const int lg   = lane >> 4;    // 0..3
    const int l7   = lane & 7;

    // XCD swizzle: xcd owns 8bm x 32bn; concurrent 32 blocks = 8bm x 4bn
    // (A 1MB + B 1MB < 4MB L2). Bijective: orig -> (xcd, idx).
    const int orig = blockIdx.x;               // 0..2047
    const int xcd  = orig & 7;
    const int idx  = orig >> 3;                // 0..255
    const int bm   = xcd * 8 + (idx & 7);      // 0..63
    const int bn   = idx >> 3;                 // 0..31

    const float s     = *scale_p;
    const float shift = s - 64.0f;

    f32x4 acc[8][2];
#pragma unroll
    for (int i = 0; i < 8; ++i)
#pragma unroll
        for (int j = 0; j < 2; ++j)
#pragma unroll
            for (int r = 0; r < 4; ++r) acc[i][j][r] = 0.0f;

    // ---------------- stage A once: 128 rows x 1KB ----------------
    // call c: wave w supplies row c*8+w entirely (64 lanes x 16B), granule
    // lane ^ (row&7) = lane ^ wave (inverse swizzle; LDS dest linear).
    {
        const uint8_t* srcA = (const uint8_t*)A
            + (size_t)(bm * 128 + wave) * 1024 + ((lane ^ wave) << 4);
        uint8_t* dA = sh + wave * 1024;
#pragma unroll
        for (int c = 0; c < 16; ++c)
            stage16(srcA + (size_t)c * 8192, dA + c * 8192);
    }
    asm volatile("s_waitcnt vmcnt(0)" ::: "memory");
    __builtin_amdgcn_s_barrier();              // the ONLY pre-epilogue barrier

    // ---------------- B pointers (direct global, per-lane) ----------------
    const uint8_t* Bp0 = (const uint8_t*)B
        + (size_t)(bn * 256 + wave * 32 + lr) * 1024;   // j=0 frag col rows
    const uint8_t* Bp1 = Bp0 + 16 * 1024;               // j=1

    bf16x8 af[2][8], bfr[2][2];

#define LOADA(D, KS) do {                                                       \
        const int _sl = ((((KS) << 2) | lg) ^ l7) << 4;                         \
        const uint8_t* _p = sh + lr * 1024 + _sl;                               \
        _Pragma("unroll")                                                       \
        for (int _i = 0; _i < 8; ++_i)                                          \
            af[D][_i] = *(const bf16x8*)(_p + _i * 16384);                      \
    } while (0)

#define LOADB(D, KS) do {                                                       \
        const int _ko = (KS) * 64 + lg * 16;                                    \
        bfr[D][0] = *(const bf16x8*)(Bp0 + _ko);                                \
        bfr[D][1] = *(const bf16x8*)(Bp1 + _ko);                                \
    } while (0)

#define MMA(D) do {                                                             \
        __builtin_amdgcn_s_setprio(1);                                          \
        _Pragma("unroll")                                                       \
        for (int _i = 0; _i < 8; ++_i)                                          \
            _Pragma("unroll")                                                   \
            for (int _j = 0; _j < 2; ++_j)                                      \
                acc[_i][_j] = MFMA16(af[D][_i], bfr[D][_j], acc[_i][_j], 0, 0, 0); \
        __builtin_amdgcn_s_setprio(0);                                          \
    } while (0)

    // ---------------- main loop: 16 k-steps, NO barriers ----------------
    LOADA(0, 0);
    LOADB(0, 0);
#pragma unroll
    for (int ks = 0; ks < 16; ++ks) {
        const int cur = ks & 1, nxt = cur ^ 1;
        if (ks < 15) { LOADA(nxt, ks + 1); LOADB(nxt, ks + 1); }
        MMA(cur);
    }
#undef LOADA
#undef LOADB
#undef MMA

    // ---------------- epilogue: exp + LDS-combined reductions ----------------
    // D layout (16x16): col = lr, row = lg*4 + r  (verified R1/R5/R7).
    __syncthreads();                           // all waves done reading A
    float* rs = (float*)sh;                    // [128] row partials
    float* cs = rs + 128;                      // [256] col partials
    if (t < 128)      rs[t] = 0.f;
    else if (t < 384) cs[t - 128] = 0.f;
    __syncthreads();

    float cp[2] = {0.f, 0.f};
#pragma unroll
    for (int i = 0; i < 8; ++i) {
        float rp[4] = {0.f, 0.f, 0.f, 0.f};
#pragma unroll
        for (int j = 0; j < 2; ++j) {
#pragma unroll
            for (int r = 0; r < 4; ++r) {
                const float logit = s * acc[i][j][r];
                const float e = __expf(logit - shift);
                rp[r] += e;
                cp[j] += e;
                const int rowg = bm * 128 + i * 16 + lg * 4 + r;
                const int colg = bn * 256 + wave * 32 + j * 16 + lr;
                if (rowg == colg) diag[rowg] = logit;
            }
        }
#pragma unroll
        for (int r = 0; r < 4; ++r) {
            float v = rp[r];
            v += __shfl_xor(v, 1);
            v += __shfl_xor(v, 2);
            v += __shfl_xor(v, 4);
            v += __shfl_xor(v, 8);
            if (lr == 0) atomicAdd(&rs[i * 16 + lg * 4 + r], v);
        }
    }
#pragma unroll
    for (int j = 0; j < 2; ++j) {
        float v = cp[j];
        v += __shfl_xor(v, 16);
        v += __shfl_xor(v, 32);
        if (lg == 0) cs[wave * 32 + j * 16 + lr] = v;   // wave-exclusive cols
    }
    __syncthreads();
    if (t < 128)      atomicAdd(&rowsum[bm * 128 + t], rs[t]);
    else if (t < 384) atomicAdd(&colsum[bn * 256 + (t - 128)], cs[t - 128]);
}

// ---------------- final reduce: loss scalar (parallel) ----------------
__global__ void clip_finalize(const float* __restrict__ rowsum, const float* __restrict__ colsum,
                              const float* __restrict__ diag, const float* __restrict__ scale_p,
                              float* __restrict__ out) {
    __shared__ float red[4];
    const float s = *scale_p;
    const float shift = s - 64.0f;
    const int i = blockIdx.x * 256 + threadIdx.x;   // grid 32 x 256 = 8192
    float acc = logf(rowsum[i]) + logf(colsum[i]) + 2.f * shift - 2.f * diag[i];
#pragma unroll
    for (int m = 1; m < 64; m <<= 1) acc += __shfl_xor(acc, m);
    const int wave = threadIdx.x >> 6;
    const int lane = threadIdx.x & 63;
    if (lane == 0) red[wave] = acc;
    __syncthreads();
    if (threadIdx.x == 0) {
        atomicAdd(out, (red[0] + red[1] + red[2] + red[3]) / (2.0f * N_ROWS));
    }
}

extern "C" void kernel_launch(void* const* d_in, const int* in_sizes, int n_in,
                              void* d_out, int out_size, void* d_ws, size_t ws_size,
                              hipStream_t stream) {
    const float* img     = (const float*)d_in[0];
    const float* txt     = (const float*)d_in[1];
    const float* scale_p = (const float*)d_in[2];

    uint8_t* ws = (uint8_t*)d_ws;
    uint16_t* Abf   = (uint16_t*)ws;                                  // 8 MB
    uint16_t* Bbf   = (uint16_t*)(ws + (size_t)8 * 1024 * 1024);      // 8 MB
    float*    rowsum = (float*)(ws + (size_t)16 * 1024 * 1024);       // 32 KB
    float*    colsum = rowsum + N_ROWS;                               // 32 KB
    float*    diag   = colsum + N_ROWS;                               // 32 KB
    float*    out    = (float*)d_out;

    hipMemsetAsync(rowsum, 0, 2 * N_ROWS * sizeof(float), stream);
    hipMemsetAsync(out, 0, sizeof(float), stream);
    convert_bf16<<<1024, 256, 0, stream>>>(img, txt, Abf, Bbf);
    clip_gemm<<<2048, 512, 0, stream>>>(Abf, Bbf, scale_p, rowsum, colsum, diag);
    clip_finalize<<<32, 256, 0, stream>>>(rowsum, colsum, diag, scale_p, out);
}